// Round 4
// baseline (329.033 us; speedup 1.0000x reference)
//
#include <hip/hip_runtime.h>

// Malvar-He-Cutler demosaic. x: (N,1,H,W) fp32 bayer mosaic -> out: (N,3,H,W) fp32.
// Memory-bound: 64 MB in + 192 MB out.
// R5 (prev session, best): LDS-staged 128x32 tile + global_load_lds DMA -> dur 244.3.
// R6 counted-vmcnt pipeline: 258.1. R7 no-LDS rolling window: 253.8.
// R8 batched-MLP (16 indep loads/thread): 247.3. Three structural rewrites within
// 5% -> my theories are unconstrained because the demosaic dispatch has NEVER
// appeared in the top-5 counter table (always just under the ~120us poison fills),
// and the dur_us decomposition is self-contradictory (R6: 258-125 => kernel 133us,
// which would have topped the table but didn't).
//
// R9 = DIAGNOSTIC ROUND (intentional dur_us regression):
//   1. Structure: R5 + register-only edge fixup (2nd barrier & LDS fixup deleted;
//      only lane tx==0 @x0==0 / tx==31 @x0==896 ever read clamp-affected LDS cols,
//      and the correct values are already in their own 8-float row).
//   2. Block (0,0,0) sleeps ~135us (40 x s_sleep(127) = 325k cyc) AFTER its stores.
//      Zero extra traffic; every demosaic dispatch becomes ~195us > all fills ->
//      its TRUE counter row (FETCH_SIZE / WRITE_SIZE / VGPR / Occupancy) enters the
//      top-5, and the graded-total shift identifies the dur_us model:
//        dur = fill + 2*kernel  -> ~509us
//        dur = fill + 1*kernel  -> ~316us
//        dur = kernel only      -> ~195us
//   R10 removes the sleep and acts on the measured traffic.

constexpr int H = 1024, W = 1024;
constexpr int TILE_W = 128, TILE_H = 32;
constexpr int LDS_W = TILE_W + 4;   // 132 floats = 528 B -> rows stay 16B-aligned
constexpr int LDS_H = TILE_H + 4;   // 36 -> 19,008 B LDS
constexpr int CHUNKS_PER_ROW = LDS_W / 4;            // 33
constexpr int N_CHUNKS = CHUNKS_PER_ROW * LDS_H;     // 1188

typedef float v4f __attribute__((ext_vector_type(4)));
typedef __attribute__((address_space(1))) const unsigned int gu32;
typedef __attribute__((address_space(3))) unsigned int lu32;

__global__ __launch_bounds__(256) void demosaic_kernel(
    const float* __restrict__ xin_all, const int* __restrict__ bp,
    float* __restrict__ out)
{
    __shared__ float tile[LDS_H][LDS_W];

    const int tx = threadIdx.x;            // 0..31 -> 4 px wide
    const int ty = threadIdx.y;            // 0..7  -> 4 rows each
    const int tid = ty * 32 + tx;
    const int x0 = blockIdx.x * TILE_W;
    const int y0 = blockIdx.y * TILE_H;
    const int n  = blockIdx.z;

    // Bayer pattern -> parity flips (uniform scalar loads).
    const int p0 = bp[0], p1 = bp[1];
    const int fi = (p0 == 2) || (p0 == 1 && p1 == 2);
    const int fj = (p0 == 2) || (p0 == 1 && p1 == 0);

    const float* __restrict__ xin = xin_all + (size_t)n * H * W;

    // Stage 132x36 tile via 16B global->LDS DMA (wave-uniform LDS base + lane*16;
    // per-lane global addresses arbitrary). Edge chunks get a clamped in-bounds
    // address; the 2 affected halo values are fixed in REGISTERS after the read.
    const int gx0 = x0 - 2;
    for (int idx = tid; idx < N_CHUNKS; idx += 256) {
        const int r = idx / CHUNKS_PER_ROW;           // magic-mul
        const int k = idx - r * CHUNKS_PER_ROW;
        const int gy = min(max(y0 + r - 2, 0), H - 1);
        const int gx = min(max(gx0 + 4 * k, 0), W - 4);
        const float* src = xin + (size_t)gy * W + gx;
        __builtin_amdgcn_global_load_lds((gu32*)src, (lu32*)&tile[r][4 * k], 16, 0, 0);
    }
    __syncthreads();   // drains vmcnt -> all DMA complete

    // Register-only edge fixup (replaces the old LDS-write fixup + 2nd barrier).
    // left  (x0==0, tx==0):  LDS row head holds {x0,x1,x2,x3}, want {x0,x0,x0,x1}
    // right (x0==896,tx==31): LDS row tail holds {x1020..x1023}, want {x1022,x1023,x1023,x1023}
    const bool lfix = (x0 == 0) && (tx == 0);
    const bool rfix = (x0 == W - TILE_W) && (tx == 31);

    const int xs  = tx * 4;
    const int ry0 = ty * 4;

    // 8x8 register window covering this thread's 4x4 patch (+/-2 halo).
    float w[8][8];
    #pragma unroll
    for (int r = 0; r < 8; ++r) {
        const v4f a = *(const v4f*)&tile[ry0 + r][xs];
        const v4f b = *(const v4f*)&tile[ry0 + r][xs + 4];
        w[r][0] = a.x; w[r][1] = a.y; w[r][2] = a.z; w[r][3] = a.w;
        w[r][4] = b.x; w[r][5] = b.y; w[r][6] = b.z; w[r][7] = b.w;
        if (lfix) { w[r][3] = w[r][1]; w[r][1] = w[r][0]; w[r][2] = w[r][0]; }
        if (rfix) { w[r][4] = w[r][6]; w[r][5] = w[r][7]; w[r][6] = w[r][7]; }
    }

    #pragma unroll
    for (int dr = 0; dr < 4; ++dr) {
        // y = y0 + ry0 + dr; y0, ry0 even -> row parity = dr&1
        const int qi = (dr & 1) ^ fi;

        float r4[4], g4[4], b4[4];
        #pragma unroll
        for (int p = 0; p < 4; ++p) {
            const float c   = w[dr + 2][p + 2];
            const float up  = w[dr + 1][p + 2], dn  = w[dr + 3][p + 2];
            const float lf  = w[dr + 2][p + 1], rt  = w[dr + 2][p + 3];
            const float up2 = w[dr + 0][p + 2], dn2 = w[dr + 4][p + 2];
            const float lf2 = w[dr + 2][p + 0], rt2 = w[dr + 2][p + 4];
            const float dg  = w[dr + 1][p + 1] + w[dr + 1][p + 3]
                            + w[dr + 3][p + 1] + w[dr + 3][p + 3];

            const float axH = lf2 + rt2;
            const float axV = up2 + dn2;
            const float ax  = axH + axV;
            const float crossHV = (up + dn) + (lf + rt);

            const float s0 = (8.0f  * c + 4.0f * crossHV   - 2.0f * ax) * 0.0625f;
            const float s1 = (12.0f * c + 4.0f * dg        - 3.0f * ax) * 0.0625f;
            const float s2 = (10.0f * c + 8.0f * (lf + rt) - 2.0f * (axH + dg) + axV) * 0.0625f;
            const float s3 = (10.0f * c + 8.0f * (up + dn) - 2.0f * (axV + dg) + axH) * 0.0625f;

            const int qj = (p & 1) ^ fj;       // x parity == p&1 (x0, xs even)
            const int qt = (qi << 1) | qj;
            r4[p] = (qt == 0) ? c  : (qt == 1) ? s2 : (qt == 2) ? s3 : s1;
            g4[p] = (qi == qj) ? s0 : c;
            b4[p] = (qt == 0) ? s1 : (qt == 1) ? s3 : (qt == 2) ? s2 : c;
        }

        const int y = y0 + ry0 + dr;
        const size_t colbase = (size_t)(x0 + xs);
        v4f* const oR = (v4f*)(out + ((size_t)(n * 3 + 0) * H + y) * W + colbase);
        v4f* const oG = (v4f*)(out + ((size_t)(n * 3 + 1) * H + y) * W + colbase);
        v4f* const oB = (v4f*)(out + ((size_t)(n * 3 + 2) * H + y) * W + colbase);
        v4f vR = { r4[0], r4[1], r4[2], r4[3] };
        v4f vG = { g4[0], g4[1], g4[2], g4[3] };
        v4f vB = { b4[0], b4[1], b4[2], b4[3] };
        __builtin_nontemporal_store(vR, oR);
        __builtin_nontemporal_store(vG, oG);
        __builtin_nontemporal_store(vB, oB);
    }

    // ---- DIAGNOSTIC: block (0,0,0) lingers ~135us so every demosaic dispatch
    // (~195us) outlasts the ~120us poison fills and surfaces its counter row.
    // Zero memory traffic; remove in R10. ----
    if (blockIdx.x == 0 && blockIdx.y == 0 && blockIdx.z == 0) {
        #pragma unroll 1
        for (int i = 0; i < 40; ++i) __builtin_amdgcn_s_sleep(127);
    }
}

extern "C" void kernel_launch(void* const* d_in, const int* in_sizes, int n_in,
                              void* d_out, int out_size, void* d_ws, size_t ws_size,
                              hipStream_t stream) {
    const float* x  = (const float*)d_in[0];
    const int*   bp = (const int*)d_in[1];
    float* out = (float*)d_out;
    const int N = in_sizes[0] / (H * W);   // 16
    dim3 grid(W / TILE_W, H / TILE_H, N);  // (8, 32, 16)
    dim3 block(32, 8, 1);
    demosaic_kernel<<<grid, block, 0, stream>>>(x, bp, out);
}

// Round 5
// 262.397 us; speedup vs baseline: 1.2540x; 1.2540x over previous
//
#include <hip/hip_runtime.h>

// Malvar-He-Cutler demosaic. x: (N,1,H,W) fp32 bayer mosaic -> out: (N,3,H,W) fp32.
// R9 diagnostic (sleep-extended dispatch) surfaced the kernel's true counters:
//   WRITE_SIZE 196.7e3 KB = exact output; FETCH 47e3 KB < input (L3-resident);
//   VGPR 44; LDS 19.5KB (8 blocks/CU fit) -- yet Occupancy 18% (~1.4 blocks/CU
//   resident) and VALUBusy 11%. Real kernel time ~121 us @ 2.07 TB/s.
// Unifying fact: R5/R8/R9 (three DIFFERENT bodies, all 4096-WG grids) all land at
//   ~121-124 us = 4096 / ~34 WG/us. Concurrency = rate x lifetime = 1.4 blocks/CU.
//   => duration is pinned by workgroup dispatch/turnover, not the kernel body.
//   The poison fill corroborates: 6.5 TB/s at 10% occupancy -- few LONG-LIVED
//   waves streaming beat many short-lived blocks.
// R10: PERSISTENT blocks. 512 WGs (2/CU), block (64,4); each block loops over 8
//   consecutive 256x16 tiles with a depth-1 pipeline of R8's independent-16-load
//   batches (A/B double-buffered in registers, statically indexed): issue next
//   tile's loads -> compute/store current. No LDS, no barriers; every wave keeps
//   ~16 loads + 12 stores in flight continuously for the whole kernel.

constexpr int H = 1024, W = 1024;

typedef float v4f  __attribute__((ext_vector_type(4)));
typedef float v4fu __attribute__((ext_vector_type(4), aligned(4)));  // 4B-aligned load

__global__ __launch_bounds__(256) void demosaic_kernel(
    const float* __restrict__ xin_all, const int* __restrict__ bp,
    float* __restrict__ out, int iters)
{
    const int tx  = threadIdx.x;                 // 0..63 -> 4 px wide
    const int ty  = threadIdx.y;                 // 0..3  -> 4 rows each
    const int txo = tx * 4;                      // col offset within 256-wide strip

    // Bayer pattern -> parity flips (uniform scalar loads).
    const int p0 = bp[0], p1 = bp[1];
    const int fi = (p0 == 2) || (p0 == 1 && p1 == 2);
    const int fj = (p0 == 2) || (p0 == 1 && p1 == 0);

    // Tile index t -> (bx, by, n): bx = t&3 (256-col strip), by = (t>>2)&63
    // (16-row band), n = t>>8 (image). Consecutive t per block = row-band sweep.
    auto LOADB = [&](v4f (&A)[8], v4f (&B)[8], int t) {
        const int bx = t & 3, by = (t >> 2) & 63, n = t >> 8;
        const int gx  = bx * 256 + txo;
        const int ry0 = by * 16 + ty * 4;
        const bool lf = (gx == 0), rf = (gx == W - 4);
        const int  xa = lf ? gx : gx - 2;        // A covers cols gx-2..gx+1
        const int  xb = rf ? gx : gx + 2;        // B covers cols gx+2..gx+5
        const float* __restrict__ img = xin_all + (size_t)n * H * W;
        #pragma unroll
        for (int r = 0; r < 8; ++r) {            // 16 independent loads
            const int gy = min(max(ry0 - 2 + r, 0), H - 1);
            const float* row = img + (size_t)gy * W;
            A[r] = *(const v4fu*)(row + xa);
            B[r] = *(const v4fu*)(row + xb);
        }
    };

    auto PROC = [&](v4f (&A)[8], v4f (&B)[8], int t) {
        const int bx = t & 3, by = (t >> 2) & 63, n = t >> 8;
        const int gx  = bx * 256 + txo;
        const int ry0 = by * 16 + ty * 4;
        const bool lf = (gx == 0), rf = (gx == W - 4);

        // 8x8 window, cols gx-2..gx+5 (edge lanes: clamped loads + selects).
        float w[8][8];
        #pragma unroll
        for (int r = 0; r < 8; ++r) {
            w[r][0] = A[r].x;
            w[r][1] = lf ? A[r].x : A[r].y;
            w[r][2] = lf ? A[r].x : A[r].z;
            w[r][3] = lf ? A[r].y : A[r].w;
            w[r][4] = rf ? B[r].z : B[r].x;
            w[r][5] = rf ? B[r].w : B[r].y;
            w[r][6] = rf ? B[r].w : B[r].z;
            w[r][7] = B[r].w;
        }

        #pragma unroll
        for (int dr = 0; dr < 4; ++dr) {
            const int qi = (dr & 1) ^ fi;        // ry0 even -> row parity = dr&1

            float r4[4], g4[4], b4[4];
            #pragma unroll
            for (int p = 0; p < 4; ++p) {
                const float c   = w[dr + 2][p + 2];
                const float up  = w[dr + 1][p + 2], dn  = w[dr + 3][p + 2];
                const float lfv = w[dr + 2][p + 1], rt  = w[dr + 2][p + 3];
                const float up2 = w[dr + 0][p + 2], dn2 = w[dr + 4][p + 2];
                const float lf2 = w[dr + 2][p + 0], rt2 = w[dr + 2][p + 4];
                const float dg  = w[dr + 1][p + 1] + w[dr + 1][p + 3]
                                + w[dr + 3][p + 1] + w[dr + 3][p + 3];

                const float axH = lf2 + rt2;
                const float axV = up2 + dn2;
                const float ax  = axH + axV;
                const float crossHV = (up + dn) + (lfv + rt);

                const float s0 = (8.0f  * c + 4.0f * crossHV    - 2.0f * ax) * 0.0625f;
                const float s1 = (12.0f * c + 4.0f * dg         - 3.0f * ax) * 0.0625f;
                const float s2 = (10.0f * c + 8.0f * (lfv + rt) - 2.0f * (axH + dg) + axV) * 0.0625f;
                const float s3 = (10.0f * c + 8.0f * (up + dn)  - 2.0f * (axV + dg) + axH) * 0.0625f;

                const int qj = (p & 1) ^ fj;     // gx even -> col parity = p&1
                const int qt = (qi << 1) | qj;
                r4[p] = (qt == 0) ? c  : (qt == 1) ? s2 : (qt == 2) ? s3 : s1;
                g4[p] = (qi == qj) ? s0 : c;
                b4[p] = (qt == 0) ? s1 : (qt == 1) ? s3 : (qt == 2) ? s2 : c;
            }

            const int y = ry0 + dr;
            const size_t rowoff = (size_t)y * W + gx;
            v4f* const oR = (v4f*)(out + (size_t)(n * 3 + 0) * H * W + rowoff);
            v4f* const oG = (v4f*)(out + (size_t)(n * 3 + 1) * H * W + rowoff);
            v4f* const oB = (v4f*)(out + (size_t)(n * 3 + 2) * H * W + rowoff);
            v4f vR = { r4[0], r4[1], r4[2], r4[3] };
            v4f vG = { g4[0], g4[1], g4[2], g4[3] };
            v4f vB = { b4[0], b4[1], b4[2], b4[3] };
            __builtin_nontemporal_store(vR, oR);
            __builtin_nontemporal_store(vG, oG);
            __builtin_nontemporal_store(vB, oB);
        }
    };

    // ---- persistent loop: depth-1 pipeline over `iters` consecutive tiles ----
    v4f A0[8], B0[8], A1[8], B1[8];
    const int t0 = blockIdx.x * iters;

    LOADB(A0, B0, t0);
    #pragma unroll 1
    for (int it = 0; it < iters; it += 2) {
        LOADB(A1, B1, t0 + it + 1);              // next tile's loads in flight...
        PROC(A0, B0, t0 + it);                   // ...under current tile's work
        if (it + 2 < iters) LOADB(A0, B0, t0 + it + 2);
        PROC(A1, B1, t0 + it + 1);
    }
}

extern "C" void kernel_launch(void* const* d_in, const int* in_sizes, int n_in,
                              void* d_out, int out_size, void* d_ws, size_t ws_size,
                              hipStream_t stream) {
    const float* x  = (const float*)d_in[0];
    const int*   bp = (const int*)d_in[1];
    float* out = (float*)d_out;
    const int N = in_sizes[0] / (H * W);         // 16
    const int ntiles = 4 * 64 * N;               // 4096
    const int blocks = 512;                      // 2 blocks/CU, persistent
    const int iters  = ntiles / blocks;          // 8 (even; pipeline assumes it)
    dim3 grid(blocks, 1, 1);
    dim3 block(64, 4, 1);                        // wave = 256-px-wide 4-row band
    demosaic_kernel<<<grid, block, 0, stream>>>(x, bp, out, iters);
}

// Round 6
// 249.692 us; speedup vs baseline: 1.3178x; 1.0509x over previous
//
#include <hip/hip_runtime.h>

// Malvar-He-Cutler demosaic. x: (N,1,H,W) fp32 bayer mosaic -> out: (N,3,H,W) fp32.
// Evidence so far (R9 diagnostic counters + 5 structural variants):
//   - traffic clean: FETCH 47MB (<input, L3-resident), WRITE 196.7e3 KB (exact);
//   - compute idle: VALUBusy 11%; VGPR 44; LDS 19.5KB;
//   - kernel ~121us = 2.07 TB/s in EVERY structure tried:
//     LDS-DMA (R5/R9), counted-vmcnt pipeline (R6), rolling window (R7),
//     batched-MLP (R8), persistent+pipelined (R10). Meanwhile the harness's
//     fillBuffer sustains 6.6 TB/s on the SAME output buffer.
//   => falsified: barrier drains, load chains, MLP, occupancy, WG turnover.
// R11: the one never-varied element is the STORE PATH: __builtin_nontemporal_store
//   to 3 planes (every variant; the 6.6 TB/s fill uses plain stores). NT streams
//   past L2 with (hypothesized) poor write aggregation, and vmcnt is IN-ORDER:
//   every later load-wait transitively waits for all earlier NT stores to reach
//   memory -> slow store retirement serializes every structure identically.
//   This round: EXACT R9 body (sleep removed), NT stores -> plain stores.
//   Single variable vs R9's profiled counters.
//   Predict: kernel 121 -> ~55-70us (graded ~175-195) if NT is the killer;
//   unchanged (~244) kills the theory -> R12 restructures store streams.

constexpr int H = 1024, W = 1024;
constexpr int TILE_W = 128, TILE_H = 32;
constexpr int LDS_W = TILE_W + 4;   // 132 floats = 528 B -> rows stay 16B-aligned
constexpr int LDS_H = TILE_H + 4;   // 36 -> 19,008 B LDS
constexpr int CHUNKS_PER_ROW = LDS_W / 4;            // 33
constexpr int N_CHUNKS = CHUNKS_PER_ROW * LDS_H;     // 1188

typedef float v4f __attribute__((ext_vector_type(4)));
typedef __attribute__((address_space(1))) const unsigned int gu32;
typedef __attribute__((address_space(3))) unsigned int lu32;

__global__ __launch_bounds__(256) void demosaic_kernel(
    const float* __restrict__ xin_all, const int* __restrict__ bp,
    float* __restrict__ out)
{
    __shared__ float tile[LDS_H][LDS_W];

    const int tx = threadIdx.x;            // 0..31 -> 4 px wide
    const int ty = threadIdx.y;            // 0..7  -> 4 rows each
    const int tid = ty * 32 + tx;
    const int x0 = blockIdx.x * TILE_W;
    const int y0 = blockIdx.y * TILE_H;
    const int n  = blockIdx.z;

    // Bayer pattern -> parity flips (uniform scalar loads).
    const int p0 = bp[0], p1 = bp[1];
    const int fi = (p0 == 2) || (p0 == 1 && p1 == 2);
    const int fj = (p0 == 2) || (p0 == 1 && p1 == 0);

    const float* __restrict__ xin = xin_all + (size_t)n * H * W;

    // Stage 132x36 tile via 16B global->LDS DMA (wave-uniform LDS base + lane*16;
    // per-lane global addresses arbitrary). Edge chunks get a clamped in-bounds
    // address; the 2 affected halo values are fixed in REGISTERS after the read.
    const int gx0 = x0 - 2;
    for (int idx = tid; idx < N_CHUNKS; idx += 256) {
        const int r = idx / CHUNKS_PER_ROW;           // magic-mul
        const int k = idx - r * CHUNKS_PER_ROW;
        const int gy = min(max(y0 + r - 2, 0), H - 1);
        const int gx = min(max(gx0 + 4 * k, 0), W - 4);
        const float* src = xin + (size_t)gy * W + gx;
        __builtin_amdgcn_global_load_lds((gu32*)src, (lu32*)&tile[r][4 * k], 16, 0, 0);
    }
    __syncthreads();   // drains vmcnt -> all DMA complete

    // Register-only edge fixup.
    // left  (x0==0, tx==0):  row head holds {x0,x1,x2,x3}, want {x0,x0,x0,x1}
    // right (x0==896,tx==31): row tail holds {x1020..x1023}, want {x1022,x1023,x1023,x1023}
    const bool lfix = (x0 == 0) && (tx == 0);
    const bool rfix = (x0 == W - TILE_W) && (tx == 31);

    const int xs  = tx * 4;
    const int ry0 = ty * 4;

    // 8x8 register window covering this thread's 4x4 patch (+/-2 halo).
    float w[8][8];
    #pragma unroll
    for (int r = 0; r < 8; ++r) {
        const v4f a = *(const v4f*)&tile[ry0 + r][xs];
        const v4f b = *(const v4f*)&tile[ry0 + r][xs + 4];
        w[r][0] = a.x; w[r][1] = a.y; w[r][2] = a.z; w[r][3] = a.w;
        w[r][4] = b.x; w[r][5] = b.y; w[r][6] = b.z; w[r][7] = b.w;
        if (lfix) { w[r][3] = w[r][1]; w[r][1] = w[r][0]; w[r][2] = w[r][0]; }
        if (rfix) { w[r][4] = w[r][6]; w[r][5] = w[r][7]; w[r][6] = w[r][7]; }
    }

    #pragma unroll
    for (int dr = 0; dr < 4; ++dr) {
        // y = y0 + ry0 + dr; y0, ry0 even -> row parity = dr&1
        const int qi = (dr & 1) ^ fi;

        float r4[4], g4[4], b4[4];
        #pragma unroll
        for (int p = 0; p < 4; ++p) {
            const float c   = w[dr + 2][p + 2];
            const float up  = w[dr + 1][p + 2], dn  = w[dr + 3][p + 2];
            const float lf  = w[dr + 2][p + 1], rt  = w[dr + 2][p + 3];
            const float up2 = w[dr + 0][p + 2], dn2 = w[dr + 4][p + 2];
            const float lf2 = w[dr + 2][p + 0], rt2 = w[dr + 2][p + 4];
            const float dg  = w[dr + 1][p + 1] + w[dr + 1][p + 3]
                            + w[dr + 3][p + 1] + w[dr + 3][p + 3];

            const float axH = lf2 + rt2;
            const float axV = up2 + dn2;
            const float ax  = axH + axV;
            const float crossHV = (up + dn) + (lf + rt);

            const float s0 = (8.0f  * c + 4.0f * crossHV   - 2.0f * ax) * 0.0625f;
            const float s1 = (12.0f * c + 4.0f * dg        - 3.0f * ax) * 0.0625f;
            const float s2 = (10.0f * c + 8.0f * (lf + rt) - 2.0f * (axH + dg) + axV) * 0.0625f;
            const float s3 = (10.0f * c + 8.0f * (up + dn) - 2.0f * (axV + dg) + axH) * 0.0625f;

            const int qj = (p & 1) ^ fj;       // x parity == p&1 (x0, xs even)
            const int qt = (qi << 1) | qj;
            r4[p] = (qt == 0) ? c  : (qt == 1) ? s2 : (qt == 2) ? s3 : s1;
            g4[p] = (qi == qj) ? s0 : c;
            b4[p] = (qt == 0) ? s1 : (qt == 1) ? s3 : (qt == 2) ? s2 : c;
        }

        const int y = y0 + ry0 + dr;
        const size_t colbase = (size_t)(x0 + xs);
        v4f* const oR = (v4f*)(out + ((size_t)(n * 3 + 0) * H + y) * W + colbase);
        v4f* const oG = (v4f*)(out + ((size_t)(n * 3 + 1) * H + y) * W + colbase);
        v4f* const oB = (v4f*)(out + ((size_t)(n * 3 + 2) * H + y) * W + colbase);
        v4f vR = { r4[0], r4[1], r4[2], r4[3] };
        v4f vG = { g4[0], g4[1], g4[2], g4[3] };
        v4f vB = { b4[0], b4[1], b4[2], b4[3] };
        *oR = vR;          // R11: plain stores (was __builtin_nontemporal_store)
        *oG = vG;
        *oB = vB;
    }
}

extern "C" void kernel_launch(void* const* d_in, const int* in_sizes, int n_in,
                              void* d_out, int out_size, void* d_ws, size_t ws_size,
                              hipStream_t stream) {
    const float* x  = (const float*)d_in[0];
    const int*   bp = (const int*)d_in[1];
    float* out = (float*)d_out;
    const int N = in_sizes[0] / (H * W);   // 16
    dim3 grid(W / TILE_W, H / TILE_H, N);  // (8, 32, 16)
    dim3 block(32, 8, 1);
    demosaic_kernel<<<grid, block, 0, stream>>>(x, bp, out);
}